// Round 2
// 346.585 us; speedup vs baseline: 1.1272x; 1.1272x over previous
//
#include <hip/hip_runtime.h>
#include <stdint.h>

#define HH 8
#define NN 256
#define DD 16
#define NWIN 64
#define LOG2E 1.44269504088896340736f

typedef __attribute__((ext_vector_type(8))) short short8;
typedef __attribute__((ext_vector_type(4))) short short4_t;
typedef __attribute__((ext_vector_type(4))) float f32x4;

static __device__ __forceinline__ unsigned short f2bf(float f) {
    union { float f; uint32_t u; } v; v.f = f;
    uint32_t u = v.u;
    uint32_t r = (u + 0x7fffu + ((u >> 16) & 1u)) >> 16;   // RTNE
    return (unsigned short)r;
}
static __device__ __forceinline__ float bf2f(uint32_t s) {
    union { uint32_t u; float f; } v; v.u = s << 16;
    return v.f;
}
// pack two POSITIVE floats to bf16x2 (round-half-up == RTNE quality for our data)
// via v_perm_b32: 2 adds + 1 perm, no inline asm.
static __device__ __forceinline__ uint32_t pack_bf16_rn(float a, float b) {
    union { float f; uint32_t u; } x, y; x.f = a; y.f = b;
    // D.byte[0:1] = (x+0x8000).byte[2:3]  (sel 0x02,0x03 -> src1)
    // D.byte[2:3] = (y+0x8000).byte[2:3]  (sel 0x06,0x07 -> src0)
    return __builtin_amdgcn_perm(y.u + 0x8000u, x.u + 0x8000u, 0x07060302u);
}

// ---------- precompute: biasD[h][it][jt][q][c][r] (bf16, pre-scaled by log2e) ----------
// strides: r:1(b0-1) c:4(b2-5) q:64(b6-7) jt:256(b8-11) it:4096(b12-15) h:65536(b16-18)
__global__ void bias_perm_kernel(const float* __restrict__ table,
                                 const int* __restrict__ index,
                                 unsigned short* __restrict__ biasD) {
    int o = blockIdx.x * 256 + threadIdx.x;   // 8*16*16*4*16*4 = 524288
    int r  = o & 3;
    int c  = (o >> 2) & 15;
    int qq = (o >> 6) & 3;
    int jt = (o >> 8) & 15;
    int it = (o >> 12) & 15;
    int h  = o >> 16;
    int i = it * 16 + c;
    int j = jt * 16 + qq * 4 + r;
    int idx = index[i * NN + j];
    biasD[o] = f2bf(table[idx * HH + h] * LOG2E);
}

// ---------- precompute: maskD[w][it][jt][q][c][r] (bf16, pre-scaled by log2e) ----------
__global__ void mask_perm_kernel(const float* __restrict__ mask,
                                 unsigned short* __restrict__ maskD) {
    __shared__ float lds[16 * 256];
    int w  = blockIdx.x >> 4;
    int it = blockIdx.x & 15;
    int tid = threadIdx.x;
    const float* src = mask + ((size_t)w * NN + it * 16) * NN;
    {
        int row = tid >> 4, col0 = (tid & 15) * 16;
        const float4* s4 = (const float4*)(src + row * NN + col0);
        float4* d4 = (float4*)(lds + row * 256 + col0);
        d4[0] = s4[0]; d4[1] = s4[1]; d4[2] = s4[2]; d4[3] = s4[3];
    }
    __syncthreads();
    unsigned short* dst = maskD + (size_t)blockIdx.x * 4096 + tid * 16;
    int base = tid * 16;
#pragma unroll
    for (int e = 0; e < 16; e++) {
        int o  = base + e;
        int r  = o & 3;
        int c  = (o >> 2) & 15;
        int qq = (o >> 6) & 3;
        int jt = (o >> 8) & 15;
        int j  = jt * 16 + qq * 4 + r;
        dst[e] = f2bf(lds[c * 256 + j] * LOG2E);
    }
}

// ---------- main fused attention: one block per (b,h) ----------
__global__ __launch_bounds__(256, 4) void attn_kernel(
    const float* __restrict__ q, const float* __restrict__ k, const float* __restrict__ v,
    const unsigned short* __restrict__ biasD, const unsigned short* __restrict__ maskD,
    float* __restrict__ out)
{
    int bh = blockIdx.x;
    int b  = bh >> 3;
    int h  = bh & 7;
    int w  = b & (NWIN - 1);
    int tid  = threadIdx.x;
    int lane = tid & 63;
    int wave = tid >> 6;
    int c    = lane & 15;
    int quad = lane >> 4;

    __shared__ unsigned short Kn[256 * 20];   // row stride 20 bf16 (40B) for bank spread
    __shared__ unsigned short Vl[4096];       // [kc][quad][d][jj] slot-permuted V, bf16

    const size_t base = (size_t)bh * (NN * DD);

    // ---- stage Kn: thread t normalizes row t ----
    {
        const float4* kr = (const float4*)(k + base + (size_t)tid * DD);
        float4 a0 = kr[0], a1 = kr[1], a2 = kr[2], a3 = kr[3];
        float x[16] = {a0.x,a0.y,a0.z,a0.w, a1.x,a1.y,a1.z,a1.w,
                       a2.x,a2.y,a2.z,a2.w, a3.x,a3.y,a3.z,a3.w};
        float ss = 0.f;
#pragma unroll
        for (int e = 0; e < 16; e++) ss += x[e] * x[e];
        float sc = 1.0f / fmaxf(sqrtf(ss), 1e-12f);
        unsigned short* dst = &Kn[tid * 20];
#pragma unroll
        for (int e = 0; e < 16; e++) dst[e] = f2bf(x[e] * sc);
    }
    // ---- stage Vl (slot-permuted, bf16, NOT normalized) ----
    {
        const float4* vr = (const float4*)(v + base + (size_t)tid * DD);
        float4 a0 = vr[0], a1 = vr[1], a2 = vr[2], a3 = vr[3];
        float x[16] = {a0.x,a0.y,a0.z,a0.w, a1.x,a1.y,a1.z,a1.w,
                       a2.x,a2.y,a2.z,a2.w, a3.x,a3.y,a3.z,a3.w};
        int j  = tid;
        int kc = j >> 5, hi = (j >> 4) & 1, qv = (j >> 2) & 3, r = j & 3;
        int jj = hi * 4 + r;
#pragma unroll
        for (int d = 0; d < 16; d++)
            Vl[((kc * 4 + qv) * 16 + d) * 8 + jj] = f2bf(x[d]);
    }
    __syncthreads();

    // ---- V fragments: A-operand V^T, loaded once, reused for all i-tiles ----
    short8 vf[8];
#pragma unroll
    for (int kc = 0; kc < 8; kc++)
        vf[kc] = *(const short8*)&Vl[((kc * 4 + quad) * 16 + c) * 8];

#pragma unroll 1
    for (int t = 0; t < 4; t++) {
        int it = wave * 4 + t;
        int i0 = it * 16;

        // ---- Q fragment (B-operand): Qn[i0+c][d=quad*8+jj], quads>=2 zero ----
        short8 qf = {0,0,0,0,0,0,0,0};
        if (quad < 2) {
            const float4* qr = (const float4*)(q + base + (size_t)(i0 + c) * DD + quad * 8);
            float4 a0 = qr[0], a1 = qr[1];
            float x[8] = {a0.x,a0.y,a0.z,a0.w, a1.x,a1.y,a1.z,a1.w};
            float ss = 0.f;
#pragma unroll
            for (int e = 0; e < 8; e++) ss += x[e] * x[e];
            ss += __shfl_xor(ss, 16);
            float sc = LOG2E / fmaxf(sqrtf(ss), 1e-12f);   // fold log2e into Q only
#pragma unroll
            for (int e = 0; e < 8; e++) qf[e] = (short)f2bf(x[e] * sc);
        }

        // ---- acc[jt] = bias + mask - 16 (MFMA C-operand; -16 is the overflow guard
        //      replacing the row-max pass: exp2 args provably <= ~15) ----
        const unsigned short* bD = biasD + (size_t)(h * 16 + it) * 4096 + quad * 64 + c * 4;
        const unsigned short* mD = maskD + (size_t)(w * 16 + it) * 4096 + quad * 64 + c * 4;
        f32x4 acc[16];
#pragma unroll
        for (int jt = 0; jt < 16; jt++) {
            uint2 bu = *(const uint2*)(bD + jt * 256);
            uint2 mu = *(const uint2*)(mD + jt * 256);
            acc[jt][0] = bf2f(bu.x & 0xffffu) + (bf2f(mu.x & 0xffffu) - 16.0f);
            acc[jt][1] = bf2f(bu.x >> 16)     + (bf2f(mu.x >> 16)     - 16.0f);
            acc[jt][2] = bf2f(bu.y & 0xffffu) + (bf2f(mu.y & 0xffffu) - 16.0f);
            acc[jt][3] = bf2f(bu.y >> 16)     + (bf2f(mu.y >> 16)     - 16.0f);
        }

        // ---- S^T tile = Kn * Qn^T + C ----
#pragma unroll
        for (int jt = 0; jt < 16; jt++) {
            short8 kf = {0,0,0,0,0,0,0,0};
            if (quad < 2) {
                const unsigned short* kp = &Kn[(jt * 16 + c) * 20 + quad * 8];
                short4_t lo = *(const short4_t*)kp;
                short4_t hi = *(const short4_t*)(kp + 4);
                kf[0]=lo[0]; kf[1]=lo[1]; kf[2]=lo[2]; kf[3]=lo[3];
                kf[4]=hi[0]; kf[5]=hi[1]; kf[6]=hi[2]; kf[7]=hi[3];
            }
            acc[jt] = __builtin_amdgcn_mfma_f32_16x16x32_bf16(kf, qf, acc[jt], 0, 0, 0);
        }

        // ---- fused: exp2 + sum + pack + PV; P unnormalized, rs applied at output ----
        float s0 = 0.f, s1 = 0.f, s2 = 0.f, s3 = 0.f;
        f32x4 xacc = {0.f, 0.f, 0.f, 0.f};
#pragma unroll
        for (int kc = 0; kc < 8; kc++) {
            float a0 = __builtin_amdgcn_exp2f(acc[kc * 2][0]);
            float a1 = __builtin_amdgcn_exp2f(acc[kc * 2][1]);
            float a2 = __builtin_amdgcn_exp2f(acc[kc * 2][2]);
            float a3 = __builtin_amdgcn_exp2f(acc[kc * 2][3]);
            float b0 = __builtin_amdgcn_exp2f(acc[kc * 2 + 1][0]);
            float b1 = __builtin_amdgcn_exp2f(acc[kc * 2 + 1][1]);
            float b2 = __builtin_amdgcn_exp2f(acc[kc * 2 + 1][2]);
            float b3 = __builtin_amdgcn_exp2f(acc[kc * 2 + 1][3]);
            s0 += a0 + b0;
            s1 += a1 + b1;
            s2 += a2 + b2;
            s3 += a3 + b3;
            union { short8 s8; uint32_t u[4]; } pp;
            pp.u[0] = pack_bf16_rn(a0, a1);
            pp.u[1] = pack_bf16_rn(a2, a3);
            pp.u[2] = pack_bf16_rn(b0, b1);
            pp.u[3] = pack_bf16_rn(b2, b3);
            xacc = __builtin_amdgcn_mfma_f32_16x16x32_bf16(vf[kc], pp.s8, xacc, 0, 0, 0);
        }
        float sum = (s0 + s1) + (s2 + s3);
        sum += __shfl_xor(sum, 16);
        sum += __shfl_xor(sum, 32);
        float rs = __builtin_amdgcn_rcpf(sum);

        // ---- direct store: xacc[r] = X[i0+c][quad*4+r]; 64B-contiguous per row ----
        float4 val;
        val.x = xacc[0] * rs;
        val.y = xacc[1] * rs;
        val.z = xacc[2] * rs;
        val.w = xacc[3] * rs;
        float4* dst = (float4*)(out + ((size_t)b * NN + (i0 + c)) * (HH * DD) + h * DD + quad * 4);
        *dst = val;
    }
}

extern "C" void kernel_launch(void* const* d_in, const int* in_sizes, int n_in,
                              void* d_out, int out_size, void* d_ws, size_t ws_size,
                              hipStream_t stream) {
    const float* q     = (const float*)d_in[0];
    const float* k     = (const float*)d_in[1];
    const float* v     = (const float*)d_in[2];
    const float* table = (const float*)d_in[3];
    const int*   index = (const int*)d_in[4];
    const float* mask  = (const float*)d_in[5];
    float* out = (float*)d_out;

    unsigned short* biasD = (unsigned short*)d_ws;                 // 524288 * 2B = 1 MB
    unsigned short* maskD = biasD + (size_t)HH * NN * NN;          // 4194304 * 2B = 8 MB

    bias_perm_kernel<<<2048, 256, 0, stream>>>(table, index, biasD);
    mask_perm_kernel<<<1024, 256, 0, stream>>>(mask, maskD);
    attn_kernel<<<4096, 256, 0, stream>>>(q, k, v, biasD, maskD, out);
}